// Round 2
// baseline (1985.351 us; speedup 1.0000x reference)
//
#include <hip/hip_runtime.h>
#include <hip/hip_bf16.h>
#include <cstdio>

typedef __bf16 bf16;
typedef __bf16 bf16x8 __attribute__((ext_vector_type(8)));
typedef float  f32x4  __attribute__((ext_vector_type(4)));

#define AS1 __attribute__((address_space(1)))
#define AS3 __attribute__((address_space(3)))

__device__ __forceinline__ void async16(void* lds, const void* g) {
    __builtin_amdgcn_global_load_lds((AS1 unsigned int*)g, (AS3 unsigned int*)lds, 16, 0, 0);
}

enum { EPI_NONE = 0, EPI_SINUS = 1, EPI_BIAS = 2 };

constexpr int BM = 128, BN = 128, BK = 32;

// C[m][n] = sum_k A[m][k] * B[n][k]   (NT gemm, both operands K-contiguous, bf16 in, CT out)
// grid: (N/BN, M/BM, batch)
template <int EPI, typename CT>
__launch_bounds__(256)
__global__ void gemm_nt(const bf16* __restrict__ A, long sA, int lda,
                        const bf16* __restrict__ B, long sB, int ldb,
                        CT* __restrict__ C, long sC, int ldc,
                        int K, int mLimit,
                        const float* __restrict__ bias)
{
    __shared__ __align__(16) bf16 As[BM * BK];
    __shared__ __align__(16) bf16 Bs[BN * BK];

    const int tid  = threadIdx.x;
    const int wave = tid >> 6;
    const int lane = tid & 63;
    const int quad = lane >> 4;
    const int l16  = lane & 15;
    const int b    = blockIdx.z;
    const int m0   = blockIdx.y * BM;
    const int n0   = blockIdx.x * BN;

    A += (long)b * sA;
    B += (long)b * sB;

    // staging: wave w covers rows [w*32, w*32+32); lane L -> row L/4, kpart (L%4)*8 elems
    const int srow = lane >> 2;
    const int scol = (lane & 3) * 8;
    const bf16* gA = A + (long)(m0 + wave * 32 + srow) * lda + scol;
    const bf16* gB = B + (long)(n0 + wave * 32 + srow) * ldb + scol;
    char* lA = (char*)As + wave * 2048;   // 32 rows * 64B
    char* lB = (char*)Bs + wave * 2048;

    const int wm = (wave >> 1) * 64;
    const int wn = (wave & 1) * 64;

    f32x4 acc[4][4] = {};

    for (int k0 = 0; k0 < K; k0 += BK) {
        __syncthreads();                       // prev-iter LDS reads done
        async16(lA,        gA);
        async16(lA + 1024, gA + (long)16 * lda);
        async16(lB,        gB);
        async16(lB + 1024, gB + (long)16 * ldb);
        gA += BK; gB += BK;
        __syncthreads();                       // drains vmcnt: tiles resident

        bf16x8 af[4], bfr[4];
        #pragma unroll
        for (int i = 0; i < 4; i++) {
            af[i]  = *(const bf16x8*)(As + (wm + i * 16 + l16) * BK + quad * 8);
            bfr[i] = *(const bf16x8*)(Bs + (wn + i * 16 + l16) * BK + quad * 8);
        }
        #pragma unroll
        for (int mi = 0; mi < 4; mi++)
            #pragma unroll
            for (int ni = 0; ni < 4; ni++)
                acc[mi][ni] = __builtin_amdgcn_mfma_f32_16x16x32_bf16(
                    af[mi], bfr[ni], acc[mi][ni], 0, 0, 0);
    }

    C += (long)b * sC;

    #pragma unroll
    for (int ni = 0; ni < 4; ni++) {
        const int col = n0 + wn + ni * 16 + l16;
        float fr = 0.f;
        if (EPI == EPI_SINUS)
            fr = __expf((float)(-(col & ~1)) * (9.210340371976184f / 1024.f)); // exp(-(2i)ln(1e4)/d)
        #pragma unroll
        for (int mi = 0; mi < 4; mi++) {
            #pragma unroll
            for (int r = 0; r < 4; r++) {
                const int row = m0 + wm + mi * 16 + quad * 4 + r; // C/D: row=quad*4+reg, col=lane&15
                float v = acc[mi][ni][r];
                if (EPI == EPI_SINUS) {
                    float ang = (float)row * fr;
                    v += (col & 1) ? cosf(ang) : sinf(ang);
                }
                if (EPI == EPI_BIAS) v += bias[row];
                if (row < mLimit)
                    C[(long)row * ldc + col] = (CT)v;
            }
        }
    }
}

// f32 -> bf16 flat convert (n % 4 == 0)
__launch_bounds__(256)
__global__ void cvt_f32_bf16(const float* __restrict__ in, bf16* __restrict__ out, int n)
{
    int i = (blockIdx.x * 256 + threadIdx.x) * 4;
    if (i < n) {
        float4 v = *(const float4*)(in + i);
        out[i]     = (bf16)v.x;
        out[i + 1] = (bf16)v.y;
        out[i + 2] = (bf16)v.z;
        out[i + 3] = (bf16)v.w;
    }
}

// batched transpose + f32->bf16: in (rows x cols) f32 -> out (cols x rows) bf16
__launch_bounds__(256)
__global__ void transpose_f32_bf16(const float* __restrict__ in, bf16* __restrict__ out,
                                   int rows, int cols)
{
    __shared__ float tile[32][33];
    const long bs = (long)rows * cols;
    in  += (long)blockIdx.z * bs;
    out += (long)blockIdx.z * bs;
    const int c0 = blockIdx.x * 32, r0 = blockIdx.y * 32;
    const int tx = threadIdx.x, ty = threadIdx.y;
    #pragma unroll
    for (int i = ty; i < 32; i += 8)
        tile[i][tx] = in[(long)(r0 + i) * cols + c0 + tx];
    __syncthreads();
    #pragma unroll
    for (int i = ty; i < 32; i += 8)
        out[(long)(c0 + i) * rows + r0 + tx] = (bf16)tile[tx][i];
}

// batched bf16 transpose: in (rows x cols) -> out (cols x rows)
__launch_bounds__(256)
__global__ void transpose_bf16(const bf16* __restrict__ in, bf16* __restrict__ out,
                               int rows, int cols)
{
    __shared__ bf16 tile[32][33];
    const long bs = (long)rows * cols;
    in  += (long)blockIdx.z * bs;
    out += (long)blockIdx.z * bs;
    const int c0 = blockIdx.x * 32, r0 = blockIdx.y * 32;
    const int tx = threadIdx.x, ty = threadIdx.y;
    #pragma unroll
    for (int i = ty; i < 32; i += 8)
        tile[i][tx] = in[(long)(r0 + i) * cols + c0 + tx];
    __syncthreads();
    #pragma unroll
    for (int i = ty; i < 32; i += 8)
        out[(long)(c0 + i) * rows + r0 + tx] = tile[tx][i];
}

// column softmax over m in [0,1023) of attn (f32, (1023,1024) per batch, batch stride 1023*1024);
// writes bf16 soft (1024,1024) per batch, row 1023 zeroed
__launch_bounds__(256)
__global__ void softmax_col(const float* __restrict__ attn, bf16* __restrict__ soft)
{
    const float* a = attn + (long)blockIdx.y * (1023l * 1024);
    bf16* s        = soft + (long)blockIdx.y * (1024l * 1024);
    const int t = blockIdx.x * 256 + threadIdx.x;

    float mx = -1e30f;
    for (int m = 0; m < 1023; m++)
        mx = fmaxf(mx, a[(long)m * 1024 + t]);
    float sum = 0.f;
    for (int m = 0; m < 1023; m++)
        sum += __expf(a[(long)m * 1024 + t] - mx);
    const float inv = 1.f / sum;
    for (int m = 0; m < 1023; m++)
        s[(long)m * 1024 + t] = (bf16)(__expf(a[(long)m * 1024 + t] - mx) * inv);
    s[1023l * 1024 + t] = (bf16)0.f;
}

extern "C" void kernel_launch(void* const* d_in, const int* in_sizes, int n_in,
                              void* d_out, int out_size, void* d_ws, size_t ws_size,
                              hipStream_t stream)
{
    const float* xs    = (const float*)d_in[0];  // (32,512,1024) f32
    const float* W_emb = (const float*)d_in[1];  // (1024,512)
    const float* W_KQ  = (const float*)d_in[2];  // (1024,1024)
    const float* W_PV  = (const float*)d_in[3];  // (1024,1024)
    const float* W_un  = (const float*)d_in[4];  // (512,1024)
    const float* b_un  = (const float*)d_in[5];  // (512,)

    float* out  = (float*)d_out;                   // (32,512,1024) f32
    float* attn = out + (size_t)32 * 512 * 1024;   // (32,1023,1024) f32

    const long MB = 1024l * 1024;

    // workspace layout (bytes), bf16 buffers
    char* ws = (char*)d_ws;
    const size_t oXsT  = 0;                        // 32*1024*512*2 = 33.5 MB
    const size_t oET   = oXsT + (size_t)33554432;  // 64 MB each below
    const size_t oEn   = oET  + (size_t)67108864;
    const size_t oQT   = oEn  + (size_t)67108864;
    const size_t oR    = oQT  + (size_t)67108864;
    const size_t oWe   = oR   + (size_t)67108864;  // weights bf16: 1+2+2+1 MB
    const size_t oWkq  = oWe  + (size_t)1048576;
    const size_t oWpv  = oWkq + (size_t)2097152;
    const size_t oWun  = oWpv + (size_t)2097152;
    const size_t need  = oWun + (size_t)1048576;
    if (ws_size < need) { fprintf(stderr, "ws too small: %zu < %zu\n", ws_size, need); return; }

    bf16* xsT   = (bf16*)(ws + oXsT);
    bf16* ET    = (bf16*)(ws + oET);
    bf16* En    = (bf16*)(ws + oEn);
    bf16* QT    = (bf16*)(ws + oQT);
    bf16* R     = (bf16*)(ws + oR);
    bf16* We    = (bf16*)(ws + oWe);
    bf16* Wkq   = (bf16*)(ws + oWkq);
    bf16* Wpv   = (bf16*)(ws + oWpv);
    bf16* Wun   = (bf16*)(ws + oWun);
    bf16* soft  = ET;   // reuse: ET dead after attn gemm
    bf16* softT = QT;   // reuse: QT dead after attn gemm
    bf16* A1T   = R;
    bf16* fT    = ET;   // reuse: soft dead after its transpose

    const dim3 tb(32, 8);
    const int BIG = 1 << 30;

    // weight converts f32 -> bf16
    cvt_f32_bf16<<<512, 256, 0, stream>>>(W_emb, We, 524288);
    cvt_f32_bf16<<<1024, 256, 0, stream>>>(W_KQ, Wkq, 1048576);
    cvt_f32_bf16<<<1024, 256, 0, stream>>>(W_PV, Wpv, 1048576);
    cvt_f32_bf16<<<512, 256, 0, stream>>>(W_un, Wun, 524288);
    // xs (512x1024 f32) -> xsT (1024x512 bf16), per batch
    transpose_f32_bf16<<<dim3(32, 16, 32), tb, 0, stream>>>(xs, xsT, 512, 1024);
    // E^T[t][d] = sum_n xsT[t][n] * We[d][n] + sinusoid(t,d)
    gemm_nt<EPI_SINUS, bf16><<<dim3(8, 8, 32), 256, 0, stream>>>(
        xsT, 512l * 1024, 512, We, 0, 512, ET, MB, 1024, 512, BIG, nullptr);
    // E^T -> E (natural [e][m])
    transpose_bf16<<<dim3(32, 32, 32), tb, 0, stream>>>(ET, En, 1024, 1024);
    // Q^T[t][d] = sum_e E^T[t][e] * Wkq[d][e]
    gemm_nt<EPI_NONE, bf16><<<dim3(8, 8, 32), 256, 0, stream>>>(
        ET, MB, 1024, Wkq, 0, 1024, QT, MB, 1024, 1024, BIG, nullptr);
    // attn[m][t] = sum_e E^T[m][e] * Q^T[t][e], rows m<1023, f32 -> d_out
    gemm_nt<EPI_NONE, float><<<dim3(8, 8, 32), 256, 0, stream>>>(
        ET, MB, 1024, QT, MB, 1024, attn, 1023l * 1024, 1024, 1024, 1023, nullptr);
    // softmax over m, bf16 soft [m][t] with row 1023 zeroed
    softmax_col<<<dim3(4, 32), dim3(256), 0, stream>>>(attn, soft);
    // soft -> soft^T [t][m]
    transpose_bf16<<<dim3(32, 32, 32), tb, 0, stream>>>(soft, softT, 1024, 1024);
    // A1^T[t][e] = sum_m soft^T[t][m] * E[e][m]
    gemm_nt<EPI_NONE, bf16><<<dim3(8, 8, 32), 256, 0, stream>>>(
        softT, MB, 1024, En, MB, 1024, A1T, MB, 1024, 1024, BIG, nullptr);
    // f_attn^T[t][d] = sum_e A1^T[t][e] * Wpv[d][e]
    gemm_nt<EPI_NONE, bf16><<<dim3(8, 8, 32), 256, 0, stream>>>(
        A1T, MB, 1024, Wpv, 0, 1024, fT, MB, 1024, 1024, BIG, nullptr);
    // out[o][t] = sum_d Wun[o][d] * f_attn^T[t][d] + b_un[o], f32 -> d_out
    gemm_nt<EPI_BIAS, float><<<dim3(8, 4, 32), 256, 0, stream>>>(
        Wun, 0, 1024, fT, MB, 1024, out, 512l * 1024, 1024, 1024, BIG, b_un);
}

// Round 3
// 1453.219 us; speedup vs baseline: 1.3662x; 1.3662x over previous
//
#include <hip/hip_runtime.h>
#include <hip/hip_bf16.h>
#include <cstdio>

typedef __bf16 bf16;
typedef __bf16 bf16x8 __attribute__((ext_vector_type(8)));
typedef float  f32x4  __attribute__((ext_vector_type(4)));

#define AS1 __attribute__((address_space(1)))
#define AS3 __attribute__((address_space(3)))

__device__ __forceinline__ void async16(void* lds, const void* g) {
    __builtin_amdgcn_global_load_lds((AS1 unsigned int*)g, (AS3 unsigned int*)lds, 16, 0, 0);
}

enum { EPI_NONE = 0, EPI_SINUS = 1, EPI_BIAS = 2 };

constexpr int BM = 128, BN = 128, BK = 32;

// C[m][n] = sum_k A[m][k] * B[n][k]   (NT gemm, both operands K-contiguous, bf16 in, CT out)
// grid: (N/BN, M/BM, batch)
template <int EPI, typename CT>
__launch_bounds__(256)
__global__ void gemm_nt(const bf16* __restrict__ A, long sA, int lda,
                        const bf16* __restrict__ B, long sB, int ldb,
                        CT* __restrict__ C, long sC, int ldc,
                        int K, int mLimit,
                        const float* __restrict__ bias)
{
    __shared__ __align__(16) bf16 As[BM * BK];
    __shared__ __align__(16) bf16 Bs[BN * BK];

    const int tid  = threadIdx.x;
    const int wave = tid >> 6;
    const int lane = tid & 63;
    const int quad = lane >> 4;
    const int l16  = lane & 15;
    const int b    = blockIdx.z;
    const int m0   = blockIdx.y * BM;
    const int n0   = blockIdx.x * BN;

    A += (long)b * sA;
    B += (long)b * sB;

    // staging: wave w covers rows [w*32, w*32+32); lane L -> row L/4, kpart (L%4)*8 elems
    const int srow = lane >> 2;
    const int scol = (lane & 3) * 8;
    const bf16* gA = A + (long)(m0 + wave * 32 + srow) * lda + scol;
    const bf16* gB = B + (long)(n0 + wave * 32 + srow) * ldb + scol;
    char* lA = (char*)As + wave * 2048;   // 32 rows * 64B
    char* lB = (char*)Bs + wave * 2048;

    const int wm = (wave >> 1) * 64;
    const int wn = (wave & 1) * 64;

    f32x4 acc[4][4] = {};

    for (int k0 = 0; k0 < K; k0 += BK) {
        __syncthreads();                       // prev-iter LDS reads done
        async16(lA,        gA);
        async16(lA + 1024, gA + (long)16 * lda);
        async16(lB,        gB);
        async16(lB + 1024, gB + (long)16 * ldb);
        gA += BK; gB += BK;
        __syncthreads();                       // drains vmcnt: tiles resident

        bf16x8 af[4], bfr[4];
        #pragma unroll
        for (int i = 0; i < 4; i++) {
            af[i]  = *(const bf16x8*)(As + (wm + i * 16 + l16) * BK + quad * 8);
            bfr[i] = *(const bf16x8*)(Bs + (wn + i * 16 + l16) * BK + quad * 8);
        }
        #pragma unroll
        for (int mi = 0; mi < 4; mi++)
            #pragma unroll
            for (int ni = 0; ni < 4; ni++)
                acc[mi][ni] = __builtin_amdgcn_mfma_f32_16x16x32_bf16(
                    af[mi], bfr[ni], acc[mi][ni], 0, 0, 0);
    }

    C += (long)b * sC;

    #pragma unroll
    for (int ni = 0; ni < 4; ni++) {
        const int col = n0 + wn + ni * 16 + l16;
        float fr = 0.f;
        if (EPI == EPI_SINUS)
            fr = __expf((float)(-(col & ~1)) * (9.210340371976184f / 1024.f)); // exp(-(2i)ln(1e4)/d)
        #pragma unroll
        for (int mi = 0; mi < 4; mi++) {
            #pragma unroll
            for (int r = 0; r < 4; r++) {
                const int row = m0 + wm + mi * 16 + quad * 4 + r; // C/D: row=quad*4+reg, col=lane&15
                float v = acc[mi][ni][r];
                if (EPI == EPI_SINUS) {
                    float ang = (float)row * fr;
                    // __sinf/__cosf: inline v_sin_f32/v_cos_f32, no libcall (libcall ABI
                    // clamped the kernel to 44 VGPRs and spilled the acc tile -> 3.7 GB scratch)
                    v += (col & 1) ? __cosf(ang) : __sinf(ang);
                }
                if (EPI == EPI_BIAS) v += bias[row];
                if (row < mLimit)
                    C[(long)row * ldc + col] = (CT)v;
            }
        }
    }
}

// f32 -> bf16 flat convert (n % 4 == 0)
__launch_bounds__(256)
__global__ void cvt_f32_bf16(const float* __restrict__ in, bf16* __restrict__ out, int n)
{
    int i = (blockIdx.x * 256 + threadIdx.x) * 4;
    if (i < n) {
        float4 v = *(const float4*)(in + i);
        out[i]     = (bf16)v.x;
        out[i + 1] = (bf16)v.y;
        out[i + 2] = (bf16)v.z;
        out[i + 3] = (bf16)v.w;
    }
}

// batched transpose + f32->bf16: in (rows x cols) f32 -> out (cols x rows) bf16
__launch_bounds__(256)
__global__ void transpose_f32_bf16(const float* __restrict__ in, bf16* __restrict__ out,
                                   int rows, int cols)
{
    __shared__ float tile[32][33];
    const long bs = (long)rows * cols;
    in  += (long)blockIdx.z * bs;
    out += (long)blockIdx.z * bs;
    const int c0 = blockIdx.x * 32, r0 = blockIdx.y * 32;
    const int tx = threadIdx.x, ty = threadIdx.y;
    #pragma unroll
    for (int i = ty; i < 32; i += 8)
        tile[i][tx] = in[(long)(r0 + i) * cols + c0 + tx];
    __syncthreads();
    #pragma unroll
    for (int i = ty; i < 32; i += 8)
        out[(long)(c0 + i) * rows + r0 + tx] = (bf16)tile[tx][i];
}

// batched bf16 transpose: in (rows x cols) -> out (cols x rows)
__launch_bounds__(256)
__global__ void transpose_bf16(const bf16* __restrict__ in, bf16* __restrict__ out,
                               int rows, int cols)
{
    __shared__ bf16 tile[32][33];
    const long bs = (long)rows * cols;
    in  += (long)blockIdx.z * bs;
    out += (long)blockIdx.z * bs;
    const int c0 = blockIdx.x * 32, r0 = blockIdx.y * 32;
    const int tx = threadIdx.x, ty = threadIdx.y;
    #pragma unroll
    for (int i = ty; i < 32; i += 8)
        tile[i][tx] = in[(long)(r0 + i) * cols + c0 + tx];
    __syncthreads();
    #pragma unroll
    for (int i = ty; i < 32; i += 8)
        out[(long)(c0 + i) * rows + r0 + tx] = tile[tx][i];
}

// column softmax over m in [0,1023) of attn (f32, (1023,1024) per batch);
// online max+sum pass, then normalize pass; writes bf16 soft (1024,1024), row 1023 zeroed
__launch_bounds__(256)
__global__ void softmax_col(const float* __restrict__ attn, bf16* __restrict__ soft)
{
    const float* a = attn + (long)blockIdx.y * (1023l * 1024);
    bf16* s        = soft + (long)blockIdx.y * (1024l * 1024);
    const int t = blockIdx.x * 256 + threadIdx.x;

    float mx = -1e30f, sum = 0.f;
    for (int m = 0; m < 1023; m++) {
        float v = a[(long)m * 1024 + t];
        if (v > mx) { sum = sum * __expf(mx - v) + 1.f; mx = v; }
        else        { sum += __expf(v - mx); }
    }
    const float inv = 1.f / sum;
    for (int m = 0; m < 1023; m++)
        s[(long)m * 1024 + t] = (bf16)(__expf(a[(long)m * 1024 + t] - mx) * inv);
    s[1023l * 1024 + t] = (bf16)0.f;
}

extern "C" void kernel_launch(void* const* d_in, const int* in_sizes, int n_in,
                              void* d_out, int out_size, void* d_ws, size_t ws_size,
                              hipStream_t stream)
{
    const float* xs    = (const float*)d_in[0];  // (32,512,1024) f32
    const float* W_emb = (const float*)d_in[1];  // (1024,512)
    const float* W_KQ  = (const float*)d_in[2];  // (1024,1024)
    const float* W_PV  = (const float*)d_in[3];  // (1024,1024)
    const float* W_un  = (const float*)d_in[4];  // (512,1024)
    const float* b_un  = (const float*)d_in[5];  // (512,)

    float* out  = (float*)d_out;                   // (32,512,1024) f32
    float* attn = out + (size_t)32 * 512 * 1024;   // (32,1023,1024) f32

    const long MB = 1024l * 1024;

    // workspace layout (bytes), bf16 buffers
    char* ws = (char*)d_ws;
    const size_t oXsT  = 0;                        // 32*1024*512*2 = 33.5 MB
    const size_t oET   = oXsT + (size_t)33554432;  // 64 MB each below
    const size_t oEn   = oET  + (size_t)67108864;
    const size_t oQT   = oEn  + (size_t)67108864;
    const size_t oR    = oQT  + (size_t)67108864;
    const size_t oWe   = oR   + (size_t)67108864;  // weights bf16: 1+2+2+1 MB
    const size_t oWkq  = oWe  + (size_t)1048576;
    const size_t oWpv  = oWkq + (size_t)2097152;
    const size_t oWun  = oWpv + (size_t)2097152;
    const size_t need  = oWun + (size_t)1048576;
    if (ws_size < need) { fprintf(stderr, "ws too small: %zu < %zu\n", ws_size, need); return; }

    bf16* xsT   = (bf16*)(ws + oXsT);
    bf16* ET    = (bf16*)(ws + oET);
    bf16* En    = (bf16*)(ws + oEn);
    bf16* QT    = (bf16*)(ws + oQT);
    bf16* R     = (bf16*)(ws + oR);
    bf16* We    = (bf16*)(ws + oWe);
    bf16* Wkq   = (bf16*)(ws + oWkq);
    bf16* Wpv   = (bf16*)(ws + oWpv);
    bf16* Wun   = (bf16*)(ws + oWun);
    bf16* soft  = ET;   // reuse: ET dead after attn gemm
    bf16* softT = QT;   // reuse: QT dead after attn gemm
    bf16* A1T   = R;
    bf16* fT    = ET;   // reuse: soft dead after its transpose

    const dim3 tb(32, 8);
    const int BIG = 1 << 30;

    // weight converts f32 -> bf16
    cvt_f32_bf16<<<512, 256, 0, stream>>>(W_emb, We, 524288);
    cvt_f32_bf16<<<1024, 256, 0, stream>>>(W_KQ, Wkq, 1048576);
    cvt_f32_bf16<<<1024, 256, 0, stream>>>(W_PV, Wpv, 1048576);
    cvt_f32_bf16<<<512, 256, 0, stream>>>(W_un, Wun, 524288);
    // xs (512x1024 f32) -> xsT (1024x512 bf16), per batch
    transpose_f32_bf16<<<dim3(32, 16, 32), tb, 0, stream>>>(xs, xsT, 512, 1024);
    // E^T[t][d] = sum_n xsT[t][n] * We[d][n] + sinusoid(t,d)
    gemm_nt<EPI_SINUS, bf16><<<dim3(8, 8, 32), 256, 0, stream>>>(
        xsT, 512l * 1024, 512, We, 0, 512, ET, MB, 1024, 512, BIG, nullptr);
    // E^T -> E (natural [e][m])
    transpose_bf16<<<dim3(32, 32, 32), tb, 0, stream>>>(ET, En, 1024, 1024);
    // Q^T[t][d] = sum_e E^T[t][e] * Wkq[d][e]
    gemm_nt<EPI_NONE, bf16><<<dim3(8, 8, 32), 256, 0, stream>>>(
        ET, MB, 1024, Wkq, 0, 1024, QT, MB, 1024, 1024, BIG, nullptr);
    // attn[m][t] = sum_e E^T[m][e] * Q^T[t][e], rows m<1023, f32 -> d_out
    gemm_nt<EPI_NONE, float><<<dim3(8, 8, 32), 256, 0, stream>>>(
        ET, MB, 1024, QT, MB, 1024, attn, 1023l * 1024, 1024, 1024, 1023, nullptr);
    // softmax over m, bf16 soft [m][t] with row 1023 zeroed
    softmax_col<<<dim3(4, 32), dim3(256), 0, stream>>>(attn, soft);
    // soft -> soft^T [t][m]
    transpose_bf16<<<dim3(32, 32, 32), tb, 0, stream>>>(soft, softT, 1024, 1024);
    // A1^T[t][e] = sum_m soft^T[t][m] * E[e][m]
    gemm_nt<EPI_NONE, bf16><<<dim3(8, 8, 32), 256, 0, stream>>>(
        softT, MB, 1024, En, MB, 1024, A1T, MB, 1024, 1024, BIG, nullptr);
    // f_attn^T[t][d] = sum_e A1^T[t][e] * Wpv[d][e]
    gemm_nt<EPI_NONE, bf16><<<dim3(8, 8, 32), 256, 0, stream>>>(
        A1T, MB, 1024, Wpv, 0, 1024, fT, MB, 1024, 1024, BIG, nullptr);
    // out[o][t] = sum_d Wun[o][d] * f_attn^T[t][d] + b_un[o], f32 -> d_out
    gemm_nt<EPI_BIAS, float><<<dim3(8, 4, 32), 256, 0, stream>>>(
        Wun, 0, 1024, fT, MB, 1024, out, 512l * 1024, 1024, 1024, BIG, b_un);
}